// Round 3
// baseline (801.628 us; speedup 1.0000x reference)
//
#include <hip/hip_runtime.h>
#include <math.h>

#define N_EDGES    1048576
#define N_CENTERS  32768
#define N_SEG      131072            // N_CENTERS * 4 species
#define N_BASIS    12

#define NBLK       128               // hist/partition blocks
#define EPB        (N_EDGES / NBLK)  // 8192 edges per block
#define NBKT       2048              // coarse buckets, 64 segments each
#define PAYCAP     1024              // staged edges per compute chunk

// ---- workspace layout ----
#define WS_BLKHIST 0                              // int[NBLK][NBKT]  (1 MB)
#define WS_TOTALS  (NBLK * NBKT * 4)              // int[NBKT]
#define WS_BASE    (WS_TOTALS + NBKT * 4)         // int[NBKT]
#define WS_RECORDS (WS_BASE + NBKT * 4)           // u32[N_EDGES]     (4 MB)
#define WS_NEEDED  (WS_RECORDS + N_EDGES * 4)

__device__ __forceinline__ void compute_edge(float x, float y, float z,
                                             float* __restrict__ ph,   // 12, scaled by NORM/r
                                             float* __restrict__ sh)   // 16
{
    const float r2    = fmaf(x, x, fmaf(y, y, z * z)) + 1e-12f;
    const float inv_r = rsqrtf(r2);
    const float r     = r2 * inv_r;
    x *= inv_r; y *= inv_r; z *= inv_r;

    const float t = 0.6283185307179586f * r;   // pi/5 * r
    float s1, c1;
    __sincosf(t, &s1, &c1);
    const float twoc = 2.0f * c1;
    const float scale = 0.17677669529663687f * inv_r;  // (1/sqrt(32)) / r
    float skm1 = 0.0f, sk = s1;
    #pragma unroll
    for (int b = 0; b < N_BASIS; ++b) {
        ph[b] = sk * scale;
        const float nxt = fmaf(twoc, sk, -skm1);
        skm1 = sk; sk = nxt;
    }

    const float x2 = x * x, y2 = y * y, z2 = z * z;
    sh[0]  = 0.28209479177387814f;
    sh[1]  = 0.4886025119029199f * y;
    sh[2]  = 0.4886025119029199f * z;
    sh[3]  = 0.4886025119029199f * x;
    sh[4]  = 1.0925484305920792f * x * y;
    sh[5]  = 1.0925484305920792f * y * z;
    sh[6]  = 0.31539156525252005f * (3.0f * z2 - 1.0f);
    sh[7]  = 1.0925484305920792f * x * z;
    sh[8]  = 0.5462742152960396f * (x2 - y2);
    sh[9]  = 0.5900435899266435f * y * (3.0f * x2 - y2);
    sh[10] = 2.890611442640554f  * x * y * z;
    sh[11] = 0.4570457994644658f * y * (5.0f * z2 - 1.0f);
    sh[12] = 0.3731763325901154f * (5.0f * z2 * z - 3.0f * z);
    sh[13] = 0.4570457994644658f * x * (5.0f * z2 - 1.0f);
    sh[14] = 1.445305721320277f  * z * (x2 - y2);
    sh[15] = 0.5900435899266435f * x * (x2 - y2);
}

// ---------- 1: per-block histogram over 2048 coarse buckets (no global atomics) ----------
__global__ __launch_bounds__(1024) void hist_kernel(
    const int* __restrict__ cidx, const int* __restrict__ sidx,
    int* __restrict__ blkhist)
{
    __shared__ int h[NBKT];
    const int t = threadIdx.x;
    #pragma unroll
    for (int i = t; i < NBKT; i += 1024) h[i] = 0;
    __syncthreads();
    const int base_e = blockIdx.x * EPB;
    #pragma unroll
    for (int k = 0; k < EPB / 1024; ++k) {
        const int e = base_e + k * 1024 + t;
        const int seg = (cidx[e] << 2) | sidx[e];
        atomicAdd(&h[seg >> 6], 1);
    }
    __syncthreads();
    #pragma unroll
    for (int i = t; i < NBKT; i += 1024)
        blkhist[blockIdx.x * NBKT + i] = h[i];
}

// ---------- 2: per-bucket exclusive scan across the 128 blocks (coalesced, in-place) ----------
__global__ __launch_bounds__(256) void scanA_kernel(
    int* __restrict__ blkhist, int* __restrict__ totals)
{
    const int bkt = blockIdx.x * 256 + threadIdx.x;   // 2048 threads, one per bucket
    int run = 0;
    for (int blk = 0; blk < NBLK; ++blk) {
        const int v = blkhist[blk * NBKT + bkt];
        blkhist[blk * NBKT + bkt] = run;
        run += v;
    }
    totals[bkt] = run;
}

// ---------- 3: exclusive scan of 2048 bucket totals ----------
__global__ __launch_bounds__(1024) void scanB_kernel(
    const int* __restrict__ totals, int* __restrict__ base)
{
    __shared__ int tmp[NBKT];
    const int t = threadIdx.x;
    const int v0 = totals[t];
    const int v1 = totals[t + 1024];
    tmp[t] = v0; tmp[t + 1024] = v1;
    __syncthreads();
    for (int d = 1; d < NBKT; d <<= 1) {
        const int a = (t >= d) ? tmp[t - d] : 0;
        const int b2 = (t + 1024 >= d) ? tmp[t + 1024 - d] : 0;
        __syncthreads();
        tmp[t] += a; tmp[t + 1024] += b2;
        __syncthreads();
    }
    base[t] = tmp[t] - v0;
    base[t + 1024] = tmp[t + 1024] - v1;
}

// ---------- 4: partition into compact CSR (only LDS atomics; line-friendly stores) ----------
__global__ __launch_bounds__(1024) void partition_kernel(
    const int* __restrict__ cidx, const int* __restrict__ sidx,
    const int* __restrict__ blkhist, const int* __restrict__ base,
    unsigned int* __restrict__ records)
{
    __shared__ int cur[NBKT];
    const int t = threadIdx.x;
    #pragma unroll
    for (int i = t; i < NBKT; i += 1024)
        cur[i] = base[i] + blkhist[blockIdx.x * NBKT + i];
    __syncthreads();
    const int base_e = blockIdx.x * EPB;
    #pragma unroll
    for (int k = 0; k < EPB / 1024; ++k) {
        const int e = base_e + k * 1024 + t;
        const int seg = (cidx[e] << 2) | sidx[e];
        const int pos = atomicAdd(&cur[seg >> 6], 1);
        records[pos] = ((unsigned)(seg & 63) << 20) | (unsigned)e;
    }
}

// ---------- 5: compute — block = bucket (16 centers); stage -> stream -> tile -> store ----------
__global__ __launch_bounds__(256) void compute_kernel(
    const unsigned int* __restrict__ records,
    const int* __restrict__ base, const int* __restrict__ totals,
    const float* __restrict__ vectors,
    const float* __restrict__ rw,    // (4,12,8)
    float* __restrict__ out)
{
    __shared__ float  tile[16 * 512];   // 32 KB output tile (16 centers)
    __shared__ float4 pay[PAYCAP];      // 16 KB staged payload

    const int t = threadIdx.x;
    const int b = blockIdx.x;           // 2048 buckets
    const int n = t & 7;                // radial index owned by this lane
    const int g = t >> 3;               // group 0..31

    // per-lane W slice
    float Wn[4][N_BASIS];
    #pragma unroll
    for (int l = 0; l < 4; ++l)
        #pragma unroll
        for (int bb = 0; bb < N_BASIS; ++bb)
            Wn[l][bb] = rw[(l * N_BASIS + bb) * 8 + n];

    // zero the tile
    #pragma unroll
    for (int i = t; i < 8192; i += 256) tile[i] = 0.0f;

    const int off = base[b];
    const int cnt = totals[b];

    for (int c0 = 0; c0 < cnt; c0 += PAYCAP) {
        const int m = (cnt - c0 < PAYCAP) ? (cnt - c0) : PAYCAP;

        // cooperative stage: records (coalesced) + vector gather (parallel, in flight)
        for (int i = t; i < m; i += 256) {
            const unsigned rec = records[off + c0 + i];
            const unsigned eid = rec & 0xFFFFFu;
            pay[i] = make_float4(vectors[3 * eid + 0], vectors[3 * eid + 1],
                                 vectors[3 * eid + 2], __int_as_float((int)(rec >> 20)));
        }
        __syncthreads();

        // stream edges in arrival order; full-lane LDS atomic accumulate
        for (int j = g; j < m; j += 32) {
            const float4 v = pay[j];
            const int sl = __float_as_int(v.w);      // 0..63

            float ph[N_BASIS], sh[16];
            compute_edge(v.x, v.y, v.z, ph, sh);

            float rad[4];
            #pragma unroll
            for (int l = 0; l < 4; ++l) {
                float a = 0.0f;
                #pragma unroll
                for (int bb = 0; bb < N_BASIS; ++bb)
                    a = fmaf(ph[bb], Wn[l][bb], a);
                rad[l] = a;
            }

            float* p = tile + (sl >> 2) * 512 + (sl & 3) * 8 + n;
            #pragma unroll
            for (int L = 0; L < 16; ++L) {
                const int l = (L == 0) ? 0 : (L < 4) ? 1 : (L < 9) ? 2 : 3;
                atomicAdd(p + L * 32, sh[L] * rad[l]);
            }
        }
        __syncthreads();   // protect pay before next chunk restages
    }

    // coalesced store of the bucket's 16 centers (32 KB)
    float4*       o4 = (float4*)(out + (size_t)b * 8192);
    const float4* t4 = (const float4*)tile;
    #pragma unroll
    for (int i = t; i < 2048; i += 256) o4[i] = t4[i];
}

// ---------- fallback: atomic kernel (used only if ws too small) ----------
__global__ __launch_bounds__(256) void atomic_kernel(
    const float* __restrict__ vectors, const float* __restrict__ rw,
    const int* __restrict__ cidx, const int* __restrict__ sidx,
    float* __restrict__ out)
{
    const int e = blockIdx.x * 256 + threadIdx.x;
    if (e >= N_EDGES) return;
    float ph[N_BASIS], sh[16];
    compute_edge(vectors[3*e], vectors[3*e+1], vectors[3*e+2], ph, sh);
    float* op = out + (size_t)cidx[e] * 512 + sidx[e] * 8;
    for (int l = 0; l < 4; ++l) {
        const int L0 = l * l;
        const int ml = 2 * l + 1;
        for (int nn = 0; nn < 8; ++nn) {
            float rad = 0.0f;
            for (int bb = 0; bb < N_BASIS; ++bb)
                rad = fmaf(ph[bb], rw[(l * N_BASIS + bb) * 8 + nn], rad);
            for (int mm = 0; mm < ml; ++mm)
                atomicAdd(op + (L0 + mm) * 32 + nn, sh[L0 + mm] * rad);
        }
    }
}

extern "C" void kernel_launch(void* const* d_in, const int* in_sizes, int n_in,
                              void* d_out, int out_size, void* d_ws, size_t ws_size,
                              hipStream_t stream) {
    const float* vectors = (const float*)d_in[0];
    const float* rw      = (const float*)d_in[1];
    const int*   cidx    = (const int*)d_in[2];
    const int*   sidx    = (const int*)d_in[3];
    float*       out     = (float*)d_out;

    if (ws_size < (size_t)WS_NEEDED) {
        hipMemsetAsync(out, 0, (size_t)out_size * sizeof(float), stream);
        hipLaunchKernelGGL(atomic_kernel, dim3(N_EDGES / 256), dim3(256), 0, stream,
                           vectors, rw, cidx, sidx, out);
        return;
    }

    char* ws = (char*)d_ws;
    int*          blkhist = (int*)(ws + WS_BLKHIST);
    int*          totals  = (int*)(ws + WS_TOTALS);
    int*          basep   = (int*)(ws + WS_BASE);
    unsigned int* records = (unsigned int*)(ws + WS_RECORDS);

    hipLaunchKernelGGL(hist_kernel,      dim3(NBLK),     dim3(1024), 0, stream, cidx, sidx, blkhist);
    hipLaunchKernelGGL(scanA_kernel,     dim3(NBKT/256), dim3(256),  0, stream, blkhist, totals);
    hipLaunchKernelGGL(scanB_kernel,     dim3(1),        dim3(1024), 0, stream, totals, basep);
    hipLaunchKernelGGL(partition_kernel, dim3(NBLK),     dim3(1024), 0, stream, cidx, sidx, blkhist, basep, records);
    hipLaunchKernelGGL(compute_kernel,   dim3(NBKT),     dim3(256),  0, stream, records, basep, totals, vectors, rw, out);
}

// Round 4
// 169.857 us; speedup vs baseline: 4.7194x; 4.7194x over previous
//
#include <hip/hip_runtime.h>
#include <math.h>

#define N_EDGES   1048576
#define N_BUCKET  1024          // bucket = seg >> 7 (128 segs / bucket)
#define SEG_PER_B 128
#define N_BASIS   12
#define CAP       2048          // per-bucket edge capacity (Poisson mean 1024)
#define HBLK      256           // hist/partition blocks
#define HEPB      (N_EDGES / HBLK)   // 4096 edges per hist/partition block

// rec = (sl << 20) | edge_id   (sl = seg & 127, edge_id < 2^20)

// ---- workspace layout (contention-free counting sort; no memset needed) ----
#define WS_BLKHIST  0                             // int[HBLK][N_BUCKET]  (1 MB)
#define WS_TOTALS   (HBLK * N_BUCKET * 4)         // int[N_BUCKET]
#define WS_OFFSETS  (WS_TOTALS + N_BUCKET * 4)    // int[N_BUCKET]
#define WS_RECORDS  (WS_OFFSETS + N_BUCKET * 4)   // u32[N_EDGES]  (4 MB)
#define WS_NEEDED   (WS_RECORDS + N_EDGES * 4)

__device__ __forceinline__ void compute_edge(float x, float y, float z,
                                             float* __restrict__ ph,   // 12, scaled by NORM/r
                                             float* __restrict__ sh)   // 16
{
    const float r2    = fmaf(x, x, fmaf(y, y, z * z)) + 1e-12f;
    const float inv_r = rsqrtf(r2);
    const float r     = r2 * inv_r;
    x *= inv_r; y *= inv_r; z *= inv_r;

    const float t = 0.6283185307179586f * r;   // pi/5 * r
    float s1, c1;
    __sincosf(t, &s1, &c1);
    const float twoc = 2.0f * c1;
    const float scale = 0.17677669529663687f * inv_r;  // (1/sqrt(32)) / r
    float skm1 = 0.0f, sk = s1;
    #pragma unroll
    for (int b = 0; b < N_BASIS; ++b) {
        ph[b] = sk * scale;
        const float nxt = fmaf(twoc, sk, -skm1);
        skm1 = sk; sk = nxt;
    }

    const float x2 = x * x, y2 = y * y, z2 = z * z;
    sh[0]  = 0.28209479177387814f;
    sh[1]  = 0.4886025119029199f * y;
    sh[2]  = 0.4886025119029199f * z;
    sh[3]  = 0.4886025119029199f * x;
    sh[4]  = 1.0925484305920792f * x * y;
    sh[5]  = 1.0925484305920792f * y * z;
    sh[6]  = 0.31539156525252005f * (3.0f * z2 - 1.0f);
    sh[7]  = 1.0925484305920792f * x * z;
    sh[8]  = 0.5462742152960396f * (x2 - y2);
    sh[9]  = 0.5900435899266435f * y * (3.0f * x2 - y2);
    sh[10] = 2.890611442640554f  * x * y * z;
    sh[11] = 0.4570457994644658f * y * (5.0f * z2 - 1.0f);
    sh[12] = 0.3731763325901154f * (5.0f * z2 * z - 3.0f * z);
    sh[13] = 0.4570457994644658f * x * (5.0f * z2 - 1.0f);
    sh[14] = 1.445305721320277f  * z * (x2 - y2);
    sh[15] = 0.5900435899266435f * x * (x2 - y2);
}

__device__ __forceinline__ void flush_seg(const float* __restrict__ acc,
                                          int b, int sl, int n,
                                          float* __restrict__ out)
{
    const int seg = b * SEG_PER_B + sl;
    float* op = out + (size_t)(seg >> 2) * 512 + (seg & 3) * 8 + n;
    #pragma unroll
    for (int L = 0; L < 16; ++L) op[L * 32] = acc[L];
}

// ---------- 1: per-block histogram (LDS only; coalesced writeout; no global atomics) ----------
__global__ __launch_bounds__(256) void hist_kernel(
    const int* __restrict__ cidx, const int* __restrict__ sidx,
    int* __restrict__ blkhist)
{
    __shared__ int h[N_BUCKET];
    const int t = threadIdx.x;
    #pragma unroll
    for (int i = t; i < N_BUCKET; i += 256) h[i] = 0;
    __syncthreads();
    const int base = blockIdx.x * HEPB;
    #pragma unroll
    for (int k = 0; k < HEPB / 256; ++k) {
        const int e = base + k * 256 + t;
        const int seg = (cidx[e] << 2) | sidx[e];
        atomicAdd(&h[seg >> 7], 1);
    }
    __syncthreads();
    #pragma unroll
    for (int i = t; i < N_BUCKET; i += 256)
        blkhist[blockIdx.x * N_BUCKET + i] = h[i];
}

// ---------- 2: per-bucket exclusive scan across the 256 hist blocks (coalesced, in-place) ----------
__global__ __launch_bounds__(64) void scanA_kernel(
    int* __restrict__ blkhist, int* __restrict__ totals)
{
    const int bkt = blockIdx.x * 64 + threadIdx.x;   // 1024 threads, one per bucket
    int run = 0;
    for (int blk = 0; blk < HBLK; ++blk) {
        const int v = blkhist[blk * N_BUCKET + bkt];
        blkhist[blk * N_BUCKET + bkt] = run;
        run += v;
    }
    totals[bkt] = run;
}

// ---------- 3: exclusive scan of 1024 bucket totals (single block, LDS) ----------
__global__ __launch_bounds__(1024) void scanB_kernel(
    const int* __restrict__ totals, int* __restrict__ offsets)
{
    __shared__ int tmp[N_BUCKET];
    const int t = threadIdx.x;
    const int orig = totals[t];
    tmp[t] = orig;
    __syncthreads();
    #pragma unroll
    for (int d = 1; d < N_BUCKET; d <<= 1) {
        const int v = (t >= d) ? tmp[t - d] : 0;
        __syncthreads();
        tmp[t] += v;
        __syncthreads();
    }
    offsets[t] = tmp[t] - orig;
}

// ---------- 4: partition (deterministic bases; LDS rank only; no global atomics) ----------
__global__ __launch_bounds__(256) void partition_kernel(
    const int* __restrict__ cidx, const int* __restrict__ sidx,
    const int* __restrict__ blkhist, const int* __restrict__ offsets,
    unsigned int* __restrict__ records)
{
    __shared__ int bb[N_BUCKET];     // offsets[bkt] + this block's base within bucket
    __shared__ int lcnt[N_BUCKET];
    const int t = threadIdx.x;
    #pragma unroll
    for (int i = t; i < N_BUCKET; i += 256) {
        bb[i] = offsets[i] + blkhist[blockIdx.x * N_BUCKET + i];
        lcnt[i] = 0;
    }
    __syncthreads();
    const int base = blockIdx.x * HEPB;
    #pragma unroll
    for (int k = 0; k < HEPB / 256; ++k) {
        const int e = base + k * 256 + t;
        const int seg = (cidx[e] << 2) | sidx[e];
        const int bkt = seg >> 7;
        const int r = atomicAdd(&lcnt[bkt], 1);
        records[bb[bkt] + r] = ((unsigned)(seg & 127) << 20) | (unsigned)e;
    }
}

// ---------- 5: compute — R0-proven: per-bucket LDS sort + register-acc group walk ----------
__global__ __launch_bounds__(256) void compute_kernel(
    const unsigned int* __restrict__ sorted_rec,
    const int* __restrict__ offsets, const int* __restrict__ counts,
    const float* __restrict__ vectors,
    const float* __restrict__ rw,    // (4,12,8)
    float* __restrict__ out)
{
    __shared__ float4 pay[CAP];                 // 32 KB
    __shared__ int shist[SEG_PER_B];
    __shared__ int soff[SEG_PER_B];
    __shared__ int scur[SEG_PER_B];

    const int t = threadIdx.x;
    const int b = blockIdx.x;
    const int n = t & 7;                        // radial index owned by this lane
    const int g = t >> 3;                       // group 0..31; owns segments 4g..4g+3

    // per-lane W slice: Wn[l][bb] = rw[(l*12+bb)*8 + n]
    float Wn[4][N_BASIS];
    #pragma unroll
    for (int l = 0; l < 4; ++l)
        #pragma unroll
        for (int bb = 0; bb < N_BASIS; ++bb)
            Wn[l][bb] = rw[(l * N_BASIS + bb) * 8 + n];

    const int off = offsets[b];
    const int cnt = counts[b];

    if (cnt > CAP) {
        // correctness-only slow path (never taken for Poisson(1024) buckets)
        #pragma unroll 1
        for (int k = 0; k < 4; ++k) {
            const int sl = g * 4 + k;
            float acc[16];
            #pragma unroll
            for (int L = 0; L < 16; ++L) acc[L] = 0.0f;
            for (int j = 0; j < cnt; ++j) {
                const unsigned rec = sorted_rec[off + j];
                if ((int)(rec >> 20) != sl) continue;
                const int eid = rec & 0xFFFFF;
                float ph[N_BASIS], sh[16];
                compute_edge(vectors[3*eid], vectors[3*eid+1], vectors[3*eid+2], ph, sh);
                float rad[4];
                #pragma unroll
                for (int l = 0; l < 4; ++l) {
                    float a = 0.0f;
                    #pragma unroll
                    for (int bb = 0; bb < N_BASIS; ++bb)
                        a = fmaf(ph[bb], Wn[l][bb], a);
                    rad[l] = a;
                }
                #pragma unroll
                for (int L = 0; L < 16; ++L) {
                    const int l = (L == 0) ? 0 : (L < 4) ? 1 : (L < 9) ? 2 : 3;
                    acc[L] = fmaf(sh[L], rad[l], acc[L]);
                }
            }
            flush_seg(acc, b, sl, n, out);
        }
        return;
    }

    if (t < SEG_PER_B) shist[t] = 0;
    __syncthreads();

    // stage recs in registers + histogram by local segment
    unsigned recs[8];
    const int iters = (cnt + 255) >> 8;         // <= 8
    #pragma unroll
    for (int it = 0; it < 8; ++it) {
        const int i = it * 256 + t;
        if (it < iters && i < cnt) {
            recs[it] = sorted_rec[off + i];
            atomicAdd(&shist[recs[it] >> 20], 1);
        }
    }
    __syncthreads();

    // exclusive scan of shist (128 entries)
    if (t < SEG_PER_B) soff[t] = shist[t];
    __syncthreads();
    #pragma unroll
    for (int d = 1; d < SEG_PER_B; d <<= 1) {
        int v = 0;
        if (t >= d && t < SEG_PER_B) v = soff[t - d];
        __syncthreads();
        if (t < SEG_PER_B) soff[t] += v;
        __syncthreads();
    }
    if (t < SEG_PER_B) {
        const int ex = soff[t] - shist[t];
        soff[t] = ex;
        scur[t] = ex;
    }
    __syncthreads();

    // place: rank + gather xyz from L2/L3-resident vectors
    #pragma unroll
    for (int it = 0; it < 8; ++it) {
        const int i = it * 256 + t;
        if (it < iters && i < cnt) {
            const unsigned rec = recs[it];
            const int sl  = rec >> 20;
            const int eid = rec & 0xFFFFF;
            const int r = atomicAdd(&scur[sl], 1);
            pay[r] = make_float4(vectors[3 * eid], vectors[3 * eid + 1],
                                 vectors[3 * eid + 2], __int_as_float(sl));
        }
    }
    __syncthreads();

    // fused scan: group g walks the concatenated edges of segments 4g..4g+3
    const int s0 = g * 4;
    const int js = soff[s0];
    const int je = (s0 + 4 < SEG_PER_B) ? soff[s0 + 4] : cnt;

    int cur = -1;
    float acc[16];
    #pragma unroll
    for (int L = 0; L < 16; ++L) acc[L] = 0.0f;

    for (int j = js; j < je; ++j) {
        const float4 v = pay[j];                // 8-lane broadcast b128
        const int sl = __float_as_int(v.w);
        if (sl != cur) {
            if (cur >= 0) {
                flush_seg(acc, b, cur, n, out);
                #pragma unroll
                for (int L = 0; L < 16; ++L) acc[L] = 0.0f;
            }
            cur = sl;
        }
        float ph[N_BASIS], sh[16];
        compute_edge(v.x, v.y, v.z, ph, sh);
        float rad[4];
        #pragma unroll
        for (int l = 0; l < 4; ++l) {
            float a = 0.0f;
            #pragma unroll
            for (int bb = 0; bb < N_BASIS; ++bb)
                a = fmaf(ph[bb], Wn[l][bb], a);
            rad[l] = a;
        }
        #pragma unroll
        for (int L = 0; L < 16; ++L) {
            const int l = (L == 0) ? 0 : (L < 4) ? 1 : (L < 9) ? 2 : 3;
            acc[L] = fmaf(sh[L], rad[l], acc[L]);
        }
    }
    if (cur >= 0) flush_seg(acc, b, cur, n, out);

    // zero-fill empty segments (output is poisoned; every element must be written)
    #pragma unroll
    for (int k = 0; k < 4; ++k) {
        const int sl = s0 + k;
        if (shist[sl] == 0) {
            float z[16];
            #pragma unroll
            for (int L = 0; L < 16; ++L) z[L] = 0.0f;
            flush_seg(z, b, sl, n, out);
        }
    }
}

// ---------- fallback: atomic kernel (used only if ws too small) ----------
__global__ __launch_bounds__(256) void atomic_kernel(
    const float* __restrict__ vectors, const float* __restrict__ rw,
    const int* __restrict__ cidx, const int* __restrict__ sidx,
    float* __restrict__ out)
{
    const int e = blockIdx.x * 256 + threadIdx.x;
    if (e >= N_EDGES) return;
    float ph[N_BASIS], sh[16];
    compute_edge(vectors[3*e], vectors[3*e+1], vectors[3*e+2], ph, sh);
    float* op = out + (size_t)cidx[e] * 512 + sidx[e] * 8;
    for (int l = 0; l < 4; ++l) {
        const int L0 = l * l;
        const int ml = 2 * l + 1;
        for (int nn = 0; nn < 8; ++nn) {
            float rad = 0.0f;
            for (int bb = 0; bb < N_BASIS; ++bb)
                rad = fmaf(ph[bb], rw[(l * N_BASIS + bb) * 8 + nn], rad);
            for (int mm = 0; mm < ml; ++mm)
                atomicAdd(op + (L0 + mm) * 32 + nn, sh[L0 + mm] * rad);
        }
    }
}

extern "C" void kernel_launch(void* const* d_in, const int* in_sizes, int n_in,
                              void* d_out, int out_size, void* d_ws, size_t ws_size,
                              hipStream_t stream) {
    const float* vectors = (const float*)d_in[0];
    const float* rw      = (const float*)d_in[1];
    const int*   cidx    = (const int*)d_in[2];
    const int*   sidx    = (const int*)d_in[3];
    float*       out     = (float*)d_out;

    if (ws_size < (size_t)WS_NEEDED) {
        hipMemsetAsync(out, 0, (size_t)out_size * sizeof(float), stream);
        hipLaunchKernelGGL(atomic_kernel, dim3(N_EDGES / 256), dim3(256), 0, stream,
                           vectors, rw, cidx, sidx, out);
        return;
    }

    char* ws = (char*)d_ws;
    int*          blkhist = (int*)(ws + WS_BLKHIST);
    int*          totals  = (int*)(ws + WS_TOTALS);
    int*          offsets = (int*)(ws + WS_OFFSETS);
    unsigned int* records = (unsigned int*)(ws + WS_RECORDS);

    hipLaunchKernelGGL(hist_kernel,      dim3(HBLK),      dim3(256),  0, stream, cidx, sidx, blkhist);
    hipLaunchKernelGGL(scanA_kernel,     dim3(N_BUCKET/64), dim3(64), 0, stream, blkhist, totals);
    hipLaunchKernelGGL(scanB_kernel,     dim3(1),         dim3(1024), 0, stream, totals, offsets);
    hipLaunchKernelGGL(partition_kernel, dim3(HBLK),      dim3(256),  0, stream, cidx, sidx, blkhist, offsets, records);
    hipLaunchKernelGGL(compute_kernel,   dim3(N_BUCKET),  dim3(256),  0, stream, records, offsets, totals, vectors, rw, out);
}